// Round 25
// baseline (225.941 us; speedup 1.0000x reference)
//
#include <hip/hip_runtime.h>
#include <hip/hip_fp16.h>

#define IN_FEAT 512
#define HID 16
#define NC 7

#define NPB    128         // nodes per bucket
#define NPB_SH 7
#define NBMAX  1024        // max buckets (n <= 131072; packing needs n < 2^20)
#define CAPB   5120        // per-bucket binned capacity (mean 4090, +16 sigma)
#define CAPS   8192        // sort-stage LDS capacity (32 KB)
#define P1_EDGES 2048      // pushed again: 1563 bin blocks -> ~7.6 blocks/CU
#define P1_EPT   8         // edges per thread (256 thr)

// ------------- fused: edge binning + x@W1, parity-interleaved roles ---------
// R21 structure; P1_EDGES 4096->2048 (the TLP knob that just gave -15us,
// pushed to the ~8-blocks/CU regime). Bin: register-batched loads, one
// returning global atomic per (block,bucket), packed entries (src | dl<<20).
__global__ __launch_bounds__(256) void k_binmm(const int* __restrict__ src,
                                               const int* __restrict__ dst,
                                               int* __restrict__ gcur,
                                               int* __restrict__ binned,
                                               const float* __restrict__ x,
                                               const float* __restrict__ W,
                                               __half* __restrict__ h1,
                                               int E, int NB, int nchunk, int n, int gN) {
    int tid = threadIdx.x;
    int idx = blockIdx.x;
    int mn = (nchunk < gN ? nchunk : gN);
    int twice = 2 * mn;
    bool isBin;
    int ridx;
    if (idx < twice) { isBin = !(idx & 1); ridx = idx >> 1; }
    else {
        int r = idx - twice;
        if (nchunk > gN) { isBin = true;  ridx = mn + r; }
        else             { isBin = false; ridx = mn + r; }
    }

    if (isBin) {
        // ------------------------------ bin role ----------------------------
        __shared__ int lcur[NBMAX];
        __shared__ int sbase[NBMAX];
        for (int b = tid; b < NB; b += 256) lcur[b] = 0;
        __syncthreads();

        int base = ridx * P1_EDGES + tid;
        int d[P1_EPT];
        int lp[P1_EPT];
#pragma unroll
        for (int i = 0; i < P1_EPT; ++i) {
            int e = base + i * 256;
            d[i] = (e < E) ? __builtin_nontemporal_load(dst + e) : -1;
        }
#pragma unroll
        for (int i = 0; i < P1_EPT; ++i) {
            if (d[i] >= 0) lp[i] = atomicAdd(&lcur[d[i] >> NPB_SH], 1);
        }
        __syncthreads();
        for (int b = tid; b < NB; b += 256) {
            int c = lcur[b];
            sbase[b] = c ? atomicAdd(&gcur[b], c) : 0;  // true totals (past CAPB too)
        }
        __syncthreads();
#pragma unroll
        for (int i = 0; i < P1_EPT; ++i) {
            if (d[i] < 0) continue;
            int e = base + i * 256;
            int s = __builtin_nontemporal_load(src + e);
            int b = d[i] >> NPB_SH;
            int pos = sbase[b] + lp[i];
            if (pos < CAPB)
                binned[(size_t)b * CAPB + pos] = s | ((d[i] & (NPB - 1)) << 20);
        }
    } else {
        // ------------------------------ gemm role ---------------------------
        // One thread per row, W wave-uniform (scalar pipe), 8 loads in flight.
        int row = ridx * 256 + tid;
        if (row >= n) return;
        const float4* xr = reinterpret_cast<const float4*>(x + (size_t)row * IN_FEAT);
        float acc[HID];
#pragma unroll
        for (int c = 0; c < HID; ++c) acc[c] = 0.0f;
        for (int kt0 = 0; kt0 < IN_FEAT / 4; kt0 += 8) {
            float4 xv[8];
#pragma unroll
            for (int j = 0; j < 8; ++j) xv[j] = xr[kt0 + j];
#pragma unroll
            for (int j = 0; j < 8; ++j) {
                const float* wk = W + (size_t)(kt0 + j) * 4 * HID;
#pragma unroll
                for (int c = 0; c < HID; ++c) acc[c] = fmaf(xv[j].x, wk[c], acc[c]);
#pragma unroll
                for (int c = 0; c < HID; ++c) acc[c] = fmaf(xv[j].y, wk[HID + c], acc[c]);
#pragma unroll
                for (int c = 0; c < HID; ++c) acc[c] = fmaf(xv[j].z, wk[2 * HID + c], acc[c]);
#pragma unroll
                for (int c = 0; c < HID; ++c) acc[c] = fmaf(xv[j].w, wk[3 * HID + c], acc[c]);
            }
        }
        unsigned u[8];
#pragma unroll
        for (int j = 0; j < 8; ++j) {
            __half2 hh = __floats2half2_rn(acc[2 * j], acc[2 * j + 1]);
            u[j] = *reinterpret_cast<unsigned*>(&hh);
        }
        uint4* hp = reinterpret_cast<uint4*>(h1 + (size_t)row * HID);
        hp[0] = make_uint4(u[0], u[1], u[2], u[3]);
        hp[1] = make_uint4(u[4], u[5], u[6], u[7]);
    }
}

// -------- pass 2: per-bucket sort + deg/off/dinv + inline bucket-base scan --
__global__ __launch_bounds__(256) void k_sort2(const int* __restrict__ binned,
                                               const int* __restrict__ gcur,
                                               int* __restrict__ off,
                                               float* __restrict__ dinv,
                                               int* __restrict__ csr,
                                               const int* __restrict__ src,
                                               const int* __restrict__ dst,
                                               int n, int E, int NB) {
    __shared__ int hist[NPB];
    __shared__ int hoff[NPB];
    __shared__ int cur[NPB];
    __shared__ int wtot[4];
    __shared__ int s_base;
    __shared__ int stage[CAPS];
    int b = blockIdx.x;
    int lo = b << NPB_SH;
    int nn = min(NPB, n - lo);
    int tid = threadIdx.x;
    int lane = tid & 63, wid = tid >> 6;
    int tot = gcur[b];

    // inline exclusive prefix over bucket totals -> base
    int pre = 0;
    for (int k = tid; k < b; k += 256) pre += gcur[k];
#pragma unroll
    for (int o = 32; o >= 1; o >>= 1) pre += __shfl_xor(pre, o, 64);
    if (lane == 0) wtot[wid] = pre;
    if (tid < NPB) { hist[tid] = 0; cur[tid] = 0; }
    __syncthreads();
    if (tid == 0) s_base = wtot[0] + wtot[1] + wtot[2] + wtot[3];
    __syncthreads();
    int base = s_base;
    bool fits = (tot <= CAPB) && (tot <= CAPS);

    const int* bb = binned + (size_t)b * CAPB;
    if (fits) {
        for (int k = tid; k < tot; k += 256)
            atomicAdd(&hist[(bb[k] >> 20) & (NPB - 1)], 1);
    } else {
        for (int e = tid; e < E; e += 256) {
            int dd = dst[e];
            if ((dd >> NPB_SH) == b) atomicAdd(&hist[dd & (NPB - 1)], 1);
        }
    }
    __syncthreads();

    int v = 0, incl = 0;
    if (tid < NPB) {
        v = hist[tid];
        incl = v;
#pragma unroll
        for (int o = 1; o < 64; o <<= 1) {
            int t = __shfl_up(incl, o, 64);
            if ((tid & 63) >= o) incl += t;
        }
        if ((tid & 63) == 63) wtot[tid >> 6] = incl;
    }
    __syncthreads();
    if (tid < NPB) {
        int ex = incl - v + ((tid >= 64) ? wtot[0] : 0);
        hoff[tid] = ex;
        if (tid < nn) {
            off[lo + tid] = base + ex;
            dinv[lo + tid] = rsqrtf((float)v + 1.0f);  // +1 = self-loop
        }
    }
    if (b == NB - 1 && tid == 0) off[n] = base + tot;  // == E (true totals)
    __syncthreads();

    if (fits) {
        for (int k = tid; k < tot; k += 256) {
            int e = bb[k];
            int dl = (e >> 20) & (NPB - 1);
            int p = hoff[dl] + atomicAdd(&cur[dl], 1);
            stage[p] = e & 0xFFFFF;
        }
        __syncthreads();
        for (int k = tid; k < tot; k += 256) csr[base + k] = stage[k];
    } else {
        for (int e = tid; e < E; e += 256) {
            int dd = dst[e];
            if ((dd >> NPB_SH) == b) {
                int dl = dd & (NPB - 1);
                int p = base + hoff[dl] + atomicAdd(&cur[dl], 1);
                csr[p] = src[e];
            }
        }
    }
}

// --------- gather layer 1 + bias + relu + @W2 (fused, 8 lanes/node) ---------
__global__ void k_gather1(const __half* __restrict__ h1, const int* __restrict__ csr_src,
                          const int* __restrict__ off, const float* __restrict__ dinv,
                          const float* __restrict__ b1, const float* __restrict__ W2,
                          float* __restrict__ h2, int n) {
    int t = blockIdx.x * blockDim.x + threadIdx.x;
    int v = t >> 3, sub = t & 7, part = sub & 3, half = sub >> 2;
    if (v >= n) return;
    float di = dinv[v];
    float dw = di * di;
    float4 acc = make_float4(0.0f, 0.0f, 0.0f, 0.0f);
    if (half == 0) {  // self-loop term once
        uint2 raw = *reinterpret_cast<const uint2*>(h1 + (size_t)v * HID + part * 4);
        __half2 q0 = *reinterpret_cast<__half2*>(&raw.x);
        __half2 q1 = *reinterpret_cast<__half2*>(&raw.y);
        float2 f0 = __half22float2(q0), f1 = __half22float2(q1);
        acc = make_float4(f0.x * dw, f0.y * dw, f1.x * dw, f1.y * dw);
    }
    int beg = off[v], end = off[v + 1];
    for (int i = beg + half; i < end; i += 2) {
        int s = csr_src[i];
        float w = dinv[s] * di;
        uint2 r2 = *reinterpret_cast<const uint2*>(h1 + (size_t)s * HID + part * 4);
        __half2 a0 = *reinterpret_cast<__half2*>(&r2.x);
        __half2 a1 = *reinterpret_cast<__half2*>(&r2.y);
        float2 g0 = __half22float2(a0), g1 = __half22float2(a1);
        acc.x = fmaf(g0.x, w, acc.x);
        acc.y = fmaf(g0.y, w, acc.y);
        acc.z = fmaf(g1.x, w, acc.z);
        acc.w = fmaf(g1.y, w, acc.w);
    }
    // merge edge-halves (lane xor 4)
    acc.x += __shfl_xor(acc.x, 4);
    acc.y += __shfl_xor(acc.y, 4);
    acc.z += __shfl_xor(acc.z, 4);
    acc.w += __shfl_xor(acc.w, 4);

    float tt[4];
    tt[0] = fmaxf(acc.x + b1[part * 4 + 0], 0.0f);
    tt[1] = fmaxf(acc.y + b1[part * 4 + 1], 0.0f);
    tt[2] = fmaxf(acc.z + b1[part * 4 + 2], 0.0f);
    tt[3] = fmaxf(acc.w + b1[part * 4 + 3], 0.0f);
    float o[NC];
#pragma unroll
    for (int c = 0; c < NC; ++c) o[c] = 0.0f;
#pragma unroll
    for (int j = 0; j < 4; ++j) {
        int k = part * 4 + j;
#pragma unroll
        for (int c = 0; c < NC; ++c) o[c] = fmaf(tt[j], W2[k * NC + c], o[c]);
    }
#pragma unroll
    for (int c = 0; c < NC; ++c) {
        o[c] += __shfl_xor(o[c], 1);
        o[c] += __shfl_xor(o[c], 2);
    }
    float4* hp = reinterpret_cast<float4*>(h2 + (size_t)v * 8);
    if (sub == 0) hp[0] = make_float4(o[0], o[1], o[2], o[3]);
    if (sub == 1) hp[1] = make_float4(o[4], o[5], o[6], 0.0f);
}

// ------- gather layer 2 + bias + log_softmax (2 lanes/node, edge parity) ----
__global__ void k_gather2(const float* __restrict__ h2, const int* __restrict__ csr_src,
                          const int* __restrict__ off, const float* __restrict__ dinv,
                          const float* __restrict__ b2, float* __restrict__ out, int n) {
    int t = blockIdx.x * blockDim.x + threadIdx.x;
    int v = t >> 1, half = t & 1;
    if (v >= n) return;
    float di = dinv[v];
    float dw = di * di;
    float4 a0 = make_float4(0.0f, 0.0f, 0.0f, 0.0f);
    float4 a1 = make_float4(0.0f, 0.0f, 0.0f, 0.0f);
    if (half == 0) {
        const float4* hr = reinterpret_cast<const float4*>(h2 + (size_t)v * 8);
        float4 s0 = hr[0], s1 = hr[1];
        a0 = make_float4(s0.x * dw, s0.y * dw, s0.z * dw, s0.w * dw);
        a1 = make_float4(s1.x * dw, s1.y * dw, s1.z * dw, 0.0f);
    }
    int beg = off[v], end = off[v + 1];
    for (int i = beg + half; i < end; i += 2) {
        int s = csr_src[i];
        float w = dinv[s] * di;
        const float4* hs = reinterpret_cast<const float4*>(h2 + (size_t)s * 8);
        float4 v0 = hs[0], v1 = hs[1];
        a0.x = fmaf(v0.x, w, a0.x);
        a0.y = fmaf(v0.y, w, a0.y);
        a0.z = fmaf(v0.z, w, a0.z);
        a0.w = fmaf(v0.w, w, a0.w);
        a1.x = fmaf(v1.x, w, a1.x);
        a1.y = fmaf(v1.y, w, a1.y);
        a1.z = fmaf(v1.z, w, a1.z);
    }
    a0.x += __shfl_xor(a0.x, 1);
    a0.y += __shfl_xor(a0.y, 1);
    a0.z += __shfl_xor(a0.z, 1);
    a0.w += __shfl_xor(a0.w, 1);
    a1.x += __shfl_xor(a1.x, 1);
    a1.y += __shfl_xor(a1.y, 1);
    a1.z += __shfl_xor(a1.z, 1);
    if (half) return;
    float z[NC];
    z[0] = a0.x + b2[0]; z[1] = a0.y + b2[1]; z[2] = a0.z + b2[2]; z[3] = a0.w + b2[3];
    z[4] = a1.x + b2[4]; z[5] = a1.y + b2[5]; z[6] = a1.z + b2[6];
    float m = z[0];
#pragma unroll
    for (int c = 1; c < NC; ++c) m = fmaxf(m, z[c]);
    float sum = 0.0f;
#pragma unroll
    for (int c = 0; c < NC; ++c) sum += expf(z[c] - m);
    float lse = logf(sum) + m;
#pragma unroll
    for (int c = 0; c < NC; ++c) out[(size_t)v * NC + c] = z[c] - lse;
}

// -----------------------------------------------------------------------------
extern "C" void kernel_launch(void* const* d_in, const int* in_sizes, int n_in,
                              void* d_out, int out_size, void* d_ws, size_t ws_size,
                              hipStream_t stream) {
    const float* x  = (const float*)d_in[0];
    const int*   ei = (const int*)d_in[1];
    const float* W1 = (const float*)d_in[2];
    const float* b1 = (const float*)d_in[3];
    const float* W2 = (const float*)d_in[4];
    const float* b2 = (const float*)d_in[5];

    int n = in_sizes[0] / IN_FEAT;
    int E = in_sizes[1] / 2;
    const int* src = ei;
    const int* dst = ei + E;
    int NB = (n + NPB - 1) >> NPB_SH;

    // ws layout. h1 must not alias binned (both live in k_binmm).
    char* p = (char*)d_ws;
    int*    binned  = (int*)p;    p += (size_t)NB * CAPB * sizeof(int);   // 16.0 MB
    __half* h1      = (__half*)p; p += (size_t)HID * n * sizeof(__half);  // 3.2 MB
    float*  h2      = (float*)p;  p += (size_t)8 * n * sizeof(float);     // 3.2 MB
    int*    csr_src = (int*)p;    p += (size_t)E * sizeof(int);           // 12.8 MB
    int*    gcur    = (int*)p;    p += (size_t)NBMAX * sizeof(int);
    int*    off     = (int*)p;    p += (size_t)(n + 1) * sizeof(int);
    float*  dinv    = (float*)p;  p += (size_t)n * sizeof(float);

    const int tb = 256;
    int gN = (n + tb - 1) / tb;
    int gN8 = ((size_t)8 * n + tb - 1) / tb;
    int gN2 = (2 * n + tb - 1) / tb;
    int nchunk = (E + P1_EDGES - 1) / P1_EDGES;

    hipMemsetAsync(gcur, 0, (size_t)NBMAX * sizeof(int), stream);
    k_binmm  <<<nchunk + gN, tb, 0, stream>>>(src, dst, gcur, binned, x, W1, h1,
                                              E, NB, nchunk, n, gN);
    k_sort2  <<<NB, tb, 0, stream>>>(binned, gcur, off, dinv, csr_src,
                                     src, dst, n, E, NB);
    k_gather1<<<gN8, tb, 0, stream>>>(h1, csr_src, off, dinv, b1, W2, h2, n);
    k_gather2<<<gN2, tb, 0, stream>>>(h2, csr_src, off, dinv, b2, (float*)d_out, n);
}

// Round 26
// 221.289 us; speedup vs baseline: 1.0210x; 1.0210x over previous
//
#include <hip/hip_runtime.h>
#include <hip/hip_fp16.h>

#define IN_FEAT 512
#define HID 16
#define NC 7

#define NPB    128         // nodes per bucket
#define NPB_SH 7
#define NBMAX  1024        // max buckets (n <= 131072; packing needs n < 2^20)
#define CAPB   5120        // per-bucket binned capacity (mean 4090, +16 sigma)
#define CAPS   8192        // sort-stage LDS capacity (32 KB)
#define P1_EDGES 4096      // verified optimum (R21: 4096 beats 2048/8192/16384)
#define P1_EPT   16        // edges per thread (256 thr)

// ------------- fused: edge binning + x@W1, parity-interleaved roles ---------
// Best-known configuration (R21, 221.6us). Bin: register-batched loads, one
// returning global atomic per (block,bucket), packed entries (src | dl<<20).
// gemm: 1 thread/row, W wave-uniform (scalar pipe), h1 stored fp16.
__global__ __launch_bounds__(256) void k_binmm(const int* __restrict__ src,
                                               const int* __restrict__ dst,
                                               int* __restrict__ gcur,
                                               int* __restrict__ binned,
                                               const float* __restrict__ x,
                                               const float* __restrict__ W,
                                               __half* __restrict__ h1,
                                               int E, int NB, int nchunk, int n, int gN) {
    int tid = threadIdx.x;
    int idx = blockIdx.x;
    int mn = (nchunk < gN ? nchunk : gN);
    int twice = 2 * mn;
    bool isBin;
    int ridx;
    if (idx < twice) { isBin = !(idx & 1); ridx = idx >> 1; }
    else {
        int r = idx - twice;
        if (nchunk > gN) { isBin = true;  ridx = mn + r; }
        else             { isBin = false; ridx = mn + r; }
    }

    if (isBin) {
        // ------------------------------ bin role ----------------------------
        __shared__ int lcur[NBMAX];
        __shared__ int sbase[NBMAX];
        for (int b = tid; b < NB; b += 256) lcur[b] = 0;
        __syncthreads();

        int base = ridx * P1_EDGES + tid;
        int d[P1_EPT];
        int lp[P1_EPT];
#pragma unroll
        for (int i = 0; i < P1_EPT; ++i) {
            int e = base + i * 256;
            d[i] = (e < E) ? __builtin_nontemporal_load(dst + e) : -1;
        }
#pragma unroll
        for (int i = 0; i < P1_EPT; ++i) {
            if (d[i] >= 0) lp[i] = atomicAdd(&lcur[d[i] >> NPB_SH], 1);
        }
        __syncthreads();
        for (int b = tid; b < NB; b += 256) {
            int c = lcur[b];
            sbase[b] = c ? atomicAdd(&gcur[b], c) : 0;  // true totals (past CAPB too)
        }
        __syncthreads();
#pragma unroll
        for (int i = 0; i < P1_EPT; ++i) {
            if (d[i] < 0) continue;
            int e = base + i * 256;
            int s = __builtin_nontemporal_load(src + e);
            int b = d[i] >> NPB_SH;
            int pos = sbase[b] + lp[i];
            if (pos < CAPB)
                binned[(size_t)b * CAPB + pos] = s | ((d[i] & (NPB - 1)) << 20);
        }
    } else {
        // ------------------------------ gemm role ---------------------------
        // One thread per row, W wave-uniform (scalar pipe), 8 loads in flight.
        int row = ridx * 256 + tid;
        if (row >= n) return;
        const float4* xr = reinterpret_cast<const float4*>(x + (size_t)row * IN_FEAT);
        float acc[HID];
#pragma unroll
        for (int c = 0; c < HID; ++c) acc[c] = 0.0f;
        for (int kt0 = 0; kt0 < IN_FEAT / 4; kt0 += 8) {
            float4 xv[8];
#pragma unroll
            for (int j = 0; j < 8; ++j) xv[j] = xr[kt0 + j];
#pragma unroll
            for (int j = 0; j < 8; ++j) {
                const float* wk = W + (size_t)(kt0 + j) * 4 * HID;
#pragma unroll
                for (int c = 0; c < HID; ++c) acc[c] = fmaf(xv[j].x, wk[c], acc[c]);
#pragma unroll
                for (int c = 0; c < HID; ++c) acc[c] = fmaf(xv[j].y, wk[HID + c], acc[c]);
#pragma unroll
                for (int c = 0; c < HID; ++c) acc[c] = fmaf(xv[j].z, wk[2 * HID + c], acc[c]);
#pragma unroll
                for (int c = 0; c < HID; ++c) acc[c] = fmaf(xv[j].w, wk[3 * HID + c], acc[c]);
            }
        }
        unsigned u[8];
#pragma unroll
        for (int j = 0; j < 8; ++j) {
            __half2 hh = __floats2half2_rn(acc[2 * j], acc[2 * j + 1]);
            u[j] = *reinterpret_cast<unsigned*>(&hh);
        }
        uint4* hp = reinterpret_cast<uint4*>(h1 + (size_t)row * HID);
        hp[0] = make_uint4(u[0], u[1], u[2], u[3]);
        hp[1] = make_uint4(u[4], u[5], u[6], u[7]);
    }
}

// -------- pass 2: per-bucket sort + deg/off/dinv + inline bucket-base scan --
__global__ __launch_bounds__(256) void k_sort2(const int* __restrict__ binned,
                                               const int* __restrict__ gcur,
                                               int* __restrict__ off,
                                               float* __restrict__ dinv,
                                               int* __restrict__ csr,
                                               const int* __restrict__ src,
                                               const int* __restrict__ dst,
                                               int n, int E, int NB) {
    __shared__ int hist[NPB];
    __shared__ int hoff[NPB];
    __shared__ int cur[NPB];
    __shared__ int wtot[4];
    __shared__ int s_base;
    __shared__ int stage[CAPS];
    int b = blockIdx.x;
    int lo = b << NPB_SH;
    int nn = min(NPB, n - lo);
    int tid = threadIdx.x;
    int lane = tid & 63, wid = tid >> 6;
    int tot = gcur[b];

    // inline exclusive prefix over bucket totals -> base
    int pre = 0;
    for (int k = tid; k < b; k += 256) pre += gcur[k];
#pragma unroll
    for (int o = 32; o >= 1; o >>= 1) pre += __shfl_xor(pre, o, 64);
    if (lane == 0) wtot[wid] = pre;
    if (tid < NPB) { hist[tid] = 0; cur[tid] = 0; }
    __syncthreads();
    if (tid == 0) s_base = wtot[0] + wtot[1] + wtot[2] + wtot[3];
    __syncthreads();
    int base = s_base;
    bool fits = (tot <= CAPB) && (tot <= CAPS);

    const int* bb = binned + (size_t)b * CAPB;
    if (fits) {
        for (int k = tid; k < tot; k += 256)
            atomicAdd(&hist[(bb[k] >> 20) & (NPB - 1)], 1);
    } else {
        for (int e = tid; e < E; e += 256) {
            int dd = dst[e];
            if ((dd >> NPB_SH) == b) atomicAdd(&hist[dd & (NPB - 1)], 1);
        }
    }
    __syncthreads();

    int v = 0, incl = 0;
    if (tid < NPB) {
        v = hist[tid];
        incl = v;
#pragma unroll
        for (int o = 1; o < 64; o <<= 1) {
            int t = __shfl_up(incl, o, 64);
            if ((tid & 63) >= o) incl += t;
        }
        if ((tid & 63) == 63) wtot[tid >> 6] = incl;
    }
    __syncthreads();
    if (tid < NPB) {
        int ex = incl - v + ((tid >= 64) ? wtot[0] : 0);
        hoff[tid] = ex;
        if (tid < nn) {
            off[lo + tid] = base + ex;
            dinv[lo + tid] = rsqrtf((float)v + 1.0f);  // +1 = self-loop
        }
    }
    if (b == NB - 1 && tid == 0) off[n] = base + tot;  // == E (true totals)
    __syncthreads();

    if (fits) {
        for (int k = tid; k < tot; k += 256) {
            int e = bb[k];
            int dl = (e >> 20) & (NPB - 1);
            int p = hoff[dl] + atomicAdd(&cur[dl], 1);
            stage[p] = e & 0xFFFFF;
        }
        __syncthreads();
        for (int k = tid; k < tot; k += 256) csr[base + k] = stage[k];
    } else {
        for (int e = tid; e < E; e += 256) {
            int dd = dst[e];
            if ((dd >> NPB_SH) == b) {
                int dl = dd & (NPB - 1);
                int p = base + hoff[dl] + atomicAdd(&cur[dl], 1);
                csr[p] = src[e];
            }
        }
    }
}

// --------- gather layer 1 + bias + relu + @W2 (fused, 8 lanes/node) ---------
__global__ void k_gather1(const __half* __restrict__ h1, const int* __restrict__ csr_src,
                          const int* __restrict__ off, const float* __restrict__ dinv,
                          const float* __restrict__ b1, const float* __restrict__ W2,
                          float* __restrict__ h2, int n) {
    int t = blockIdx.x * blockDim.x + threadIdx.x;
    int v = t >> 3, sub = t & 7, part = sub & 3, half = sub >> 2;
    if (v >= n) return;
    float di = dinv[v];
    float dw = di * di;
    float4 acc = make_float4(0.0f, 0.0f, 0.0f, 0.0f);
    if (half == 0) {  // self-loop term once
        uint2 raw = *reinterpret_cast<const uint2*>(h1 + (size_t)v * HID + part * 4);
        __half2 q0 = *reinterpret_cast<__half2*>(&raw.x);
        __half2 q1 = *reinterpret_cast<__half2*>(&raw.y);
        float2 f0 = __half22float2(q0), f1 = __half22float2(q1);
        acc = make_float4(f0.x * dw, f0.y * dw, f1.x * dw, f1.y * dw);
    }
    int beg = off[v], end = off[v + 1];
    for (int i = beg + half; i < end; i += 2) {
        int s = csr_src[i];
        float w = dinv[s] * di;
        uint2 r2 = *reinterpret_cast<const uint2*>(h1 + (size_t)s * HID + part * 4);
        __half2 a0 = *reinterpret_cast<__half2*>(&r2.x);
        __half2 a1 = *reinterpret_cast<__half2*>(&r2.y);
        float2 g0 = __half22float2(a0), g1 = __half22float2(a1);
        acc.x = fmaf(g0.x, w, acc.x);
        acc.y = fmaf(g0.y, w, acc.y);
        acc.z = fmaf(g1.x, w, acc.z);
        acc.w = fmaf(g1.y, w, acc.w);
    }
    // merge edge-halves (lane xor 4)
    acc.x += __shfl_xor(acc.x, 4);
    acc.y += __shfl_xor(acc.y, 4);
    acc.z += __shfl_xor(acc.z, 4);
    acc.w += __shfl_xor(acc.w, 4);

    float tt[4];
    tt[0] = fmaxf(acc.x + b1[part * 4 + 0], 0.0f);
    tt[1] = fmaxf(acc.y + b1[part * 4 + 1], 0.0f);
    tt[2] = fmaxf(acc.z + b1[part * 4 + 2], 0.0f);
    tt[3] = fmaxf(acc.w + b1[part * 4 + 3], 0.0f);
    float o[NC];
#pragma unroll
    for (int c = 0; c < NC; ++c) o[c] = 0.0f;
#pragma unroll
    for (int j = 0; j < 4; ++j) {
        int k = part * 4 + j;
#pragma unroll
        for (int c = 0; c < NC; ++c) o[c] = fmaf(tt[j], W2[k * NC + c], o[c]);
    }
#pragma unroll
    for (int c = 0; c < NC; ++c) {
        o[c] += __shfl_xor(o[c], 1);
        o[c] += __shfl_xor(o[c], 2);
    }
    float4* hp = reinterpret_cast<float4*>(h2 + (size_t)v * 8);
    if (sub == 0) hp[0] = make_float4(o[0], o[1], o[2], o[3]);
    if (sub == 1) hp[1] = make_float4(o[4], o[5], o[6], 0.0f);
}

// ------- gather layer 2 + bias + log_softmax (2 lanes/node, edge parity) ----
__global__ void k_gather2(const float* __restrict__ h2, const int* __restrict__ csr_src,
                          const int* __restrict__ off, const float* __restrict__ dinv,
                          const float* __restrict__ b2, float* __restrict__ out, int n) {
    int t = blockIdx.x * blockDim.x + threadIdx.x;
    int v = t >> 1, half = t & 1;
    if (v >= n) return;
    float di = dinv[v];
    float dw = di * di;
    float4 a0 = make_float4(0.0f, 0.0f, 0.0f, 0.0f);
    float4 a1 = make_float4(0.0f, 0.0f, 0.0f, 0.0f);
    if (half == 0) {
        const float4* hr = reinterpret_cast<const float4*>(h2 + (size_t)v * 8);
        float4 s0 = hr[0], s1 = hr[1];
        a0 = make_float4(s0.x * dw, s0.y * dw, s0.z * dw, s0.w * dw);
        a1 = make_float4(s1.x * dw, s1.y * dw, s1.z * dw, 0.0f);
    }
    int beg = off[v], end = off[v + 1];
    for (int i = beg + half; i < end; i += 2) {
        int s = csr_src[i];
        float w = dinv[s] * di;
        const float4* hs = reinterpret_cast<const float4*>(h2 + (size_t)s * 8);
        float4 v0 = hs[0], v1 = hs[1];
        a0.x = fmaf(v0.x, w, a0.x);
        a0.y = fmaf(v0.y, w, a0.y);
        a0.z = fmaf(v0.z, w, a0.z);
        a0.w = fmaf(v0.w, w, a0.w);
        a1.x = fmaf(v1.x, w, a1.x);
        a1.y = fmaf(v1.y, w, a1.y);
        a1.z = fmaf(v1.z, w, a1.z);
    }
    a0.x += __shfl_xor(a0.x, 1);
    a0.y += __shfl_xor(a0.y, 1);
    a0.z += __shfl_xor(a0.z, 1);
    a0.w += __shfl_xor(a0.w, 1);
    a1.x += __shfl_xor(a1.x, 1);
    a1.y += __shfl_xor(a1.y, 1);
    a1.z += __shfl_xor(a1.z, 1);
    if (half) return;
    float z[NC];
    z[0] = a0.x + b2[0]; z[1] = a0.y + b2[1]; z[2] = a0.z + b2[2]; z[3] = a0.w + b2[3];
    z[4] = a1.x + b2[4]; z[5] = a1.y + b2[5]; z[6] = a1.z + b2[6];
    float m = z[0];
#pragma unroll
    for (int c = 1; c < NC; ++c) m = fmaxf(m, z[c]);
    float sum = 0.0f;
#pragma unroll
    for (int c = 0; c < NC; ++c) sum += expf(z[c] - m);
    float lse = logf(sum) + m;
#pragma unroll
    for (int c = 0; c < NC; ++c) out[(size_t)v * NC + c] = z[c] - lse;
}

// -----------------------------------------------------------------------------
extern "C" void kernel_launch(void* const* d_in, const int* in_sizes, int n_in,
                              void* d_out, int out_size, void* d_ws, size_t ws_size,
                              hipStream_t stream) {
    const float* x  = (const float*)d_in[0];
    const int*   ei = (const int*)d_in[1];
    const float* W1 = (const float*)d_in[2];
    const float* b1 = (const float*)d_in[3];
    const float* W2 = (const float*)d_in[4];
    const float* b2 = (const float*)d_in[5];

    int n = in_sizes[0] / IN_FEAT;
    int E = in_sizes[1] / 2;
    const int* src = ei;
    const int* dst = ei + E;
    int NB = (n + NPB - 1) >> NPB_SH;

    // ws layout. h1 must not alias binned (both live in k_binmm).
    char* p = (char*)d_ws;
    int*    binned  = (int*)p;    p += (size_t)NB * CAPB * sizeof(int);   // 16.0 MB
    __half* h1      = (__half*)p; p += (size_t)HID * n * sizeof(__half);  // 3.2 MB
    float*  h2      = (float*)p;  p += (size_t)8 * n * sizeof(float);     // 3.2 MB
    int*    csr_src = (int*)p;    p += (size_t)E * sizeof(int);           // 12.8 MB
    int*    gcur    = (int*)p;    p += (size_t)NBMAX * sizeof(int);
    int*    off     = (int*)p;    p += (size_t)(n + 1) * sizeof(int);
    float*  dinv    = (float*)p;  p += (size_t)n * sizeof(float);

    const int tb = 256;
    int gN = (n + tb - 1) / tb;
    int gN8 = ((size_t)8 * n + tb - 1) / tb;
    int gN2 = (2 * n + tb - 1) / tb;
    int nchunk = (E + P1_EDGES - 1) / P1_EDGES;

    hipMemsetAsync(gcur, 0, (size_t)NBMAX * sizeof(int), stream);
    k_binmm  <<<nchunk + gN, tb, 0, stream>>>(src, dst, gcur, binned, x, W1, h1,
                                              E, NB, nchunk, n, gN);
    k_sort2  <<<NB, tb, 0, stream>>>(binned, gcur, off, dinv, csr_src,
                                     src, dst, n, E, NB);
    k_gather1<<<gN8, tb, 0, stream>>>(h1, csr_src, off, dinv, b1, W2, h2, n);
    k_gather2<<<gN2, tb, 0, stream>>>(h2, csr_src, off, dinv, b2, (float*)d_out, n);
}